// Round 2
// baseline (70.268 us; speedup 1.0000x reference)
//
#include <hip/hip_runtime.h>

#define RPB 64       // rows (batch elements) per block = 1 wave
#define XDIM 99      // floats per input row
#define NJ 26        // joints in output
#define NCH 4        // input chunks per row
#define CHF 24       // floats per chunk (24*4 = 96 covers all used floats 0..95)
#define LSTR 25      // LDS row stride in floats (odd -> 2-way bank access, free)

__device__ __forceinline__ void rodrigues(float ax, float ay, float az, float* R) {
    const float EPS = 1.1920928955078125e-07f;   // np.finfo(np.float32).eps
    float t = sqrtf(ax*ax + ay*ay + az*az);
    float inv = 1.0f / (t + EPS);
    float r0 = ax*inv, r1 = ay*inv, r2 = az*inv;
    float s = __sinf(t);
    float c = __cosf(t);
    float omc = 1.0f - c;
    float r00 = r0*r0, r11 = r1*r1, r22 = r2*r2;
    float r01 = r0*r1, r02 = r0*r2, r12 = r1*r2;
    R[0] = 1.0f - omc*(r11 + r22);
    R[1] = -s*r2 + omc*r01;
    R[2] =  s*r1 + omc*r02;
    R[3] =  s*r2 + omc*r01;
    R[4] = 1.0f - omc*(r00 + r22);
    R[5] = -s*r0 + omc*r12;
    R[6] = -s*r1 + omc*r02;
    R[7] =  s*r0 + omc*r12;
    R[8] = 1.0f - omc*(r00 + r11);
}

__global__ __launch_bounds__(RPB) void skel_fk(const float* __restrict__ x,
                                               const float* __restrict__ off,
                                               float* __restrict__ out) {
    __shared__ float lds[RPB * LSTR];
    const int t = threadIdx.x;
    const int row0 = blockIdx.x * RPB;

    const float* row = &lds[t * LSTR];           // floats [24p, 24p+24) of this row
    float* orow = out + (row0 + t) * (NJ * 3);

    // slot tables (slot 0 = hip, slots 1..25 follow ORDER)
    constexpr int OFF_IDX[NJ] = {0,1,2,3,4,6,7,8,9,11,12,13,14,15,16,17,18,19,20,22,24,25,26,27,28,30};
    constexpr int PAR[NJ]     = {-1,0,1,2,3,0,5,6,7,0,9,10,11,12,10,14,15,16,17,17,10,20,21,22,23,23};
    // slots whose input triplet lives in chunk p: [SLO[p], SHI[p]] inclusive
    constexpr int SLO[NCH] = {1, 6, 13, 20};
    constexpr int SHI[NCH] = {5, 12, 19, 25};

    float ang[NJ][9];
    float px[NJ], py[NJ], pz[NJ];

    #pragma unroll
    for (int p = 0; p < NCH; ++p) {
        if (p) __syncthreads();                  // readers of previous chunk done
        // ---- stage chunk p: coalesced scalar dword loads ----
        #pragma unroll
        for (int j = 0; j < CHF; ++j) {
            int m = t + j * RPB;                 // 0..1535
            int r = m / CHF;                     // const divisor -> magic mul
            int q = m - r * CHF;
            lds[r * LSTR + q] = x[(row0 + r) * XDIM + p * CHF + q];
        }
        __syncthreads();

        if (p == 0) {
            px[0] = off[0] + row[0];
            py[0] = off[1] + row[1];
            pz[0] = off[2] + row[2];
            rodrigues(row[3], row[4], row[5], ang[0]);
            orow[0] = px[0]; orow[1] = py[0]; orow[2] = pz[0];
        }

        #pragma unroll
        for (int s = SLO[p]; s <= SHI[p]; ++s) {
            const int i  = OFF_IDX[s];
            const int pa = PAR[s];
            const int col = 3*i + 3 - p*CHF;     // compile-time constant in [0,22]
            float L[9];
            rodrigues(row[col], row[col+1], row[col+2], L);

            const float o0 = off[3*i], o1 = off[3*i+1], o2 = off[3*i+2];
            px[s] = o0*ang[pa][0] + o1*ang[pa][3] + o2*ang[pa][6] + px[pa];
            py[s] = o0*ang[pa][1] + o1*ang[pa][4] + o2*ang[pa][7] + py[pa];
            pz[s] = o0*ang[pa][2] + o1*ang[pa][5] + o2*ang[pa][8] + pz[pa];

            #pragma unroll
            for (int j = 0; j < 3; ++j) {
                #pragma unroll
                for (int k = 0; k < 3; ++k) {
                    ang[s][3*j+k] = L[3*j+0]*ang[pa][0+k]
                                  + L[3*j+1]*ang[pa][3+k]
                                  + L[3*j+2]*ang[pa][6+k];
                }
            }

            orow[s*3+0] = px[s];
            orow[s*3+1] = py[s];
            orow[s*3+2] = pz[s];
        }
    }
}

extern "C" void kernel_launch(void* const* d_in, const int* in_sizes, int n_in,
                              void* d_out, int out_size, void* d_ws, size_t ws_size,
                              hipStream_t stream) {
    const float* x   = (const float*)d_in[0];
    const float* off = (const float*)d_in[1];
    float* out = (float*)d_out;
    const int B = in_sizes[0] / XDIM;      // 262144
    const int grid = B / RPB;              // 4096
    skel_fk<<<grid, RPB, 0, stream>>>(x, off, out);
}

// Round 3
// 55.559 us; speedup vs baseline: 1.2647x; 1.2647x over previous
//
#include <hip/hip_runtime.h>

#define RPB 64       // rows per block = 1 wave
#define XDIM 99      // floats per input row
#define NJ 26        // joints in output
#define OUTF (NJ*3)  // 78 output floats per row

__device__ __forceinline__ void rodrigues(float ax, float ay, float az, float* R) {
    const float EPS = 1.1920928955078125e-07f;   // np.finfo(np.float32).eps
    float t = sqrtf(ax*ax + ay*ay + az*az);
    float inv = 1.0f / (t + EPS);
    float r0 = ax*inv, r1 = ay*inv, r2 = az*inv;
    float s = __sinf(t);
    float c = __cosf(t);
    float omc = 1.0f - c;
    float r00 = r0*r0, r11 = r1*r1, r22 = r2*r2;
    float r01 = r0*r1, r02 = r0*r2, r12 = r1*r2;
    R[0] = 1.0f - omc*(r11 + r22);
    R[1] = -s*r2 + omc*r01;
    R[2] =  s*r1 + omc*r02;
    R[3] =  s*r2 + omc*r01;
    R[4] = 1.0f - omc*(r00 + r22);
    R[5] = -s*r0 + omc*r12;
    R[6] = -s*r1 + omc*r02;
    R[7] =  s*r0 + omc*r12;
    R[8] = 1.0f - omc*(r00 + r11);
}

__global__ __launch_bounds__(RPB) void skel_fk(const float* __restrict__ x,
                                               const float* __restrict__ off,
                                               float* __restrict__ out) {
    __shared__ float buf[RPB * XDIM];            // 25344 B
    const int t = threadIdx.x;
    const int row0 = blockIdx.x * RPB;

    // ---- stage 64 full rows as one flat float4 region (block base 16B-aligned:
    //      64*99*4 = 25344 ≡ 0 mod 16) ----
    {
        const int nf4 = RPB * XDIM / 4;          // 1584
        const float4* src4 = reinterpret_cast<const float4*>(x + (long long)row0 * XDIM);
        float4* dst4 = reinterpret_cast<float4*>(buf);
        #pragma unroll
        for (int j = 0; j < (nf4 + RPB - 1) / RPB; ++j) {   // 25 iters
            int k = t + j * RPB;
            if (k < nf4) dst4[k] = src4[k];
        }
    }
    __syncthreads();

    float* row = &buf[t * XDIM];   // read floats [3i+3,3i+6); write pos[s] at [3s,3s+3)
                                   // safe: i = OFF_IDX[s] >= s, so writes land only on
                                   // already-consumed floats, below every future read.

    // slot tables (slot 0 = hip, slots 1..25 follow ORDER)
    constexpr int OFF_IDX[NJ] = {0,1,2,3,4,6,7,8,9,11,12,13,14,15,16,17,18,19,20,22,24,25,26,27,28,30};
    constexpr int PAR[NJ]     = {-1,0,1,2,3,0,5,6,7,0,9,10,11,12,10,14,15,16,17,17,10,20,21,22,23,23};

    float ang[NJ][9];
    float px[NJ], py[NJ], pz[NJ];

    // hip: consume floats 0..5, write pos[0] at floats 0..2
    px[0] = off[0] + row[0];
    py[0] = off[1] + row[1];
    pz[0] = off[2] + row[2];
    rodrigues(row[3], row[4], row[5], ang[0]);
    row[0] = px[0]; row[1] = py[0]; row[2] = pz[0];

    #pragma unroll
    for (int s = 1; s < NJ; ++s) {
        const int i  = OFF_IDX[s];
        const int pa = PAR[s];
        float L[9];
        rodrigues(row[3*i+3], row[3*i+4], row[3*i+5], L);

        const float o0 = off[3*i], o1 = off[3*i+1], o2 = off[3*i+2];
        px[s] = o0*ang[pa][0] + o1*ang[pa][3] + o2*ang[pa][6] + px[pa];
        py[s] = o0*ang[pa][1] + o1*ang[pa][4] + o2*ang[pa][7] + py[pa];
        pz[s] = o0*ang[pa][2] + o1*ang[pa][5] + o2*ang[pa][8] + pz[pa];

        #pragma unroll
        for (int j = 0; j < 3; ++j) {
            #pragma unroll
            for (int k = 0; k < 3; ++k) {
                ang[s][3*j+k] = L[3*j+0]*ang[pa][0+k]
                              + L[3*j+1]*ang[pa][3+k]
                              + L[3*j+2]*ang[pa][6+k];
            }
        }

        // in-place: floats [3s,3s+3) are dead (3s+2 < 3i+3 since i >= s)
        row[3*s+0] = px[s];
        row[3*s+1] = py[s];
        row[3*s+2] = pz[s];
    }
    __syncthreads();

    // ---- coalesced flush: out dword m of this block's region <- buf[(m/78)*99 + m%78]
    //      consecutive lanes -> consecutive global dwords (perfect coalescing);
    //      LDS reads are consecutive dwords -> conflict-free. ----
    {
        float* oblk = out + (long long)row0 * OUTF;
        #pragma unroll
        for (int j = 0; j < OUTF; ++j) {         // 78 iters, 64*78 = 4992 exact
            int m = t + j * RPB;
            int r = m / OUTF;                    // const divisor -> magic mul
            int c = m - r * OUTF;
            oblk[m] = buf[r * XDIM + c];
        }
    }
}

extern "C" void kernel_launch(void* const* d_in, const int* in_sizes, int n_in,
                              void* d_out, int out_size, void* d_ws, size_t ws_size,
                              hipStream_t stream) {
    const float* x   = (const float*)d_in[0];
    const float* off = (const float*)d_in[1];
    float* out = (float*)d_out;
    const int B = in_sizes[0] / XDIM;      // 262144
    const int grid = B / RPB;              // 4096
    skel_fk<<<grid, RPB, 0, stream>>>(x, off, out);
}

// Round 5
// 45.324 us; speedup vs baseline: 1.5504x; 1.2258x over previous
//
#include <hip/hip_runtime.h>

#define ROWS 64              // rows per block
#define TPB  (ROWS*3)        // 192 threads: 3 lanes per row (one matrix column each)
#define XDIM 99
#define NJ 26
#define OUTF (NJ*3)

__device__ __forceinline__ void rodrigues(float ax, float ay, float az, float* R) {
    const float EPS = 1.1920928955078125e-07f;   // np.finfo(np.float32).eps
    float t = sqrtf(ax*ax + ay*ay + az*az);
    float inv = 1.0f / (t + EPS);
    float r0 = ax*inv, r1 = ay*inv, r2 = az*inv;
    float s = __sinf(t);
    float c = __cosf(t);
    float omc = 1.0f - c;
    float r00 = r0*r0, r11 = r1*r1, r22 = r2*r2;
    float r01 = r0*r1, r02 = r0*r2, r12 = r1*r2;
    R[0] = 1.0f - omc*(r11 + r22);
    R[1] = -s*r2 + omc*r01;
    R[2] =  s*r1 + omc*r02;
    R[3] =  s*r2 + omc*r01;
    R[4] = 1.0f - omc*(r00 + r22);
    R[5] = -s*r0 + omc*r12;
    R[6] = -s*r1 + omc*r02;
    R[7] =  s*r0 + omc*r12;
    R[8] = 1.0f - omc*(r00 + r11);
}

__global__ __launch_bounds__(TPB, 5) void skel_fk(const float* __restrict__ x,
                                                  const float* __restrict__ off,
                                                  float* __restrict__ out) {
    __shared__ float buf[ROWS * XDIM];           // 25344 B -> 6 blocks/CU -> 18 waves/CU
    const int t = threadIdx.x;
    const int row0 = blockIdx.x * ROWS;

    // ---- stage 64 rows, flat coalesced float4 (block base 16B-aligned) ----
    {
        const int nf4 = ROWS * XDIM / 4;         // 1584
        const float4* src4 = reinterpret_cast<const float4*>(x + (long long)row0 * XDIM);
        float4* dst4 = reinterpret_cast<float4*>(buf);
        #pragma unroll
        for (int j = 0; j < 9; ++j) {            // 192*8 = 1536, +48 tail
            int m = t + j * TPB;
            if (m < nf4) dst4[m] = src4[m];
        }
    }
    __syncthreads();

    const int r = t / 3;                         // row within block
    const int k = t - 3 * r;                     // matrix column owned by this lane
    float* row = &buf[r * XDIM];

    // slot tables (slot 0 = hip, slots 1..25 follow ORDER)
    constexpr int OFF_IDX[NJ] = {0,1,2,3,4,6,7,8,9,11,12,13,14,15,16,17,18,19,20,22,24,25,26,27,28,30};
    constexpr int PAR[NJ]     = {-1,0,1,2,3,0,5,6,7,0,9,10,11,12,10,14,15,16,17,17,10,20,21,22,23,23};

    float ac[NJ][3];   // column k of ang[slot] (compile-time indices -> registers)
    float pp[NJ];      // component k of pos[slot] (kept in registers; no LDS writes
                       // during compute -> no cross-wave in-place hazard)

    // hip: full R, then select column k via cndmask (no runtime array index)
    {
        float R[9];
        rodrigues(row[3], row[4], row[5], R);
        ac[0][0] = (k == 0) ? R[0] : ((k == 1) ? R[1] : R[2]);
        ac[0][1] = (k == 0) ? R[3] : ((k == 1) ? R[4] : R[5]);
        ac[0][2] = (k == 0) ? R[6] : ((k == 1) ? R[7] : R[8]);
        pp[0] = off[k] + row[k];                 // dynamic loads, legal
    }

    #pragma unroll
    for (int s = 1; s < NJ; ++s) {
        const int i  = OFF_IDX[s];
        const int pa = PAR[s];
        float L[9];
        rodrigues(row[3*i+3], row[3*i+4], row[3*i+5], L);  // redundant across 3 lanes

        const float o0 = off[3*i], o1 = off[3*i+1], o2 = off[3*i+2];  // uniform -> s_load
        pp[s] = o0*ac[pa][0] + o1*ac[pa][1] + o2*ac[pa][2] + pp[pa];
        ac[s][0] = L[0]*ac[pa][0] + L[1]*ac[pa][1] + L[2]*ac[pa][2];
        ac[s][1] = L[3]*ac[pa][0] + L[4]*ac[pa][1] + L[5]*ac[pa][2];
        ac[s][2] = L[6]*ac[pa][0] + L[7]*ac[pa][1] + L[8]*ac[pa][2];
    }

    // all reads of buf done by every wave before any overwrite
    __syncthreads();

    // ---- write phase: pos components into the (dead) input region ----
    #pragma unroll
    for (int s = 0; s < NJ; ++s) {
        row[3*s + k] = pp[s];                    // banks (3r+k+3s) mod 32: ~2-way, free
    }
    __syncthreads();

    // ---- coalesced flush: consecutive lanes -> consecutive global dwords ----
    {
        float* oblk = out + (long long)row0 * OUTF;
        #pragma unroll
        for (int j = 0; j < 26; ++j) {           // 192*26 = 4992 exact
            int m = t + j * TPB;
            int rr = m / OUTF;                   // const divisor -> magic mul
            int c = m - rr * OUTF;
            oblk[m] = buf[rr * XDIM + c];
        }
    }
}

extern "C" void kernel_launch(void* const* d_in, const int* in_sizes, int n_in,
                              void* d_out, int out_size, void* d_ws, size_t ws_size,
                              hipStream_t stream) {
    const float* x   = (const float*)d_in[0];
    const float* off = (const float*)d_in[1];
    float* out = (float*)d_out;
    const int B = in_sizes[0] / XDIM;      // 262144
    const int grid = B / ROWS;             // 4096
    skel_fk<<<grid, TPB, 0, stream>>>(x, off, out);
}